// Round 1
// baseline (767.650 us; speedup 1.0000x reference)
//
#include <hip/hip_runtime.h>
#include <hip/hip_bf16.h>

typedef __bf16 bf16_t;
typedef bf16_t bf16x8 __attribute__((ext_vector_type(8)));
typedef float f32x4 __attribute__((ext_vector_type(4)));

constexpr int BM = 128, BN = 128, BK = 32;
constexpr int D_DIM = 1024;
constexpr int S_DIM = 4096;
constexpr int B_DIM = 4;

// ---------------- elementwise cast X: fp32 -> bf16 ----------------
__global__ void cast_f32_bf16(const float* __restrict__ in, bf16_t* __restrict__ out) {
  size_t i = ((size_t)blockIdx.x * blockDim.x + threadIdx.x) * 8;
  float4 a = *(const float4*)(in + i);
  float4 b = *(const float4*)(in + i + 4);
  bf16x8 o;
  o[0] = (bf16_t)a.x; o[1] = (bf16_t)a.y; o[2] = (bf16_t)a.z; o[3] = (bf16_t)a.w;
  o[4] = (bf16_t)b.x; o[5] = (bf16_t)b.y; o[6] = (bf16_t)b.z; o[7] = (bf16_t)b.w;
  *(bf16x8*)(out + i) = o;
}

// ---------------- transpose + cast weight: [1024][1024] f32 -> [1024][1024] bf16 (transposed) ----
__global__ void transpose_cast_1024(const float* __restrict__ in, bf16_t* __restrict__ out) {
  __shared__ float t[32][33];
  int x0 = blockIdx.x * 32, y0 = blockIdx.y * 32;
#pragma unroll
  for (int i = 0; i < 32; i += 8)
    t[threadIdx.y + i][threadIdx.x] =
        in[(size_t)(y0 + threadIdx.y + i) * D_DIM + (x0 + threadIdx.x)];
  __syncthreads();
#pragma unroll
  for (int i = 0; i < 32; i += 8)
    out[(size_t)(x0 + threadIdx.y + i) * D_DIM + (y0 + threadIdx.x)] =
        (bf16_t)t[threadIdx.x][threadIdx.y + i];
}

// ---------------- staging: 128x32 bf16 tile -> LDS via global_load_lds (16B/lane) ---------
__device__ __forceinline__ void stage128x32(const bf16_t* __restrict__ g, int ld,
                                            bf16_t* lds, int tid) {
  // lane tid covers row r=tid>>2 (then +64), col chunk (tid&3)*8
  int w = tid >> 6;
  int r = tid >> 2;
  int c = (tid & 3) * 8;
  const bf16_t* g0 = g + (size_t)r * ld + c;
  const bf16_t* g1 = g0 + (size_t)64 * ld;
  bf16_t* l0 = lds + w * 512;  // wave-uniform base; HW adds lane*16B
  __builtin_amdgcn_global_load_lds((const __attribute__((address_space(1))) void*)g0,
                                   (__attribute__((address_space(3))) void*)l0, 16, 0, 0);
  __builtin_amdgcn_global_load_lds((const __attribute__((address_space(1))) void*)g1,
                                   (__attribute__((address_space(3))) void*)(l0 + 2048), 16, 0, 0);
}

// ---------------- gemm_bt: C[M,N] = A[M,K] * Bt[N,K]^T, bf16 in, fp32 acc ---------
// EPI: 0 = bf16 out + bias        (Q,K projection)
//      1 = bf16 out + bias, transposed per batch into Vt[b][n][s]   (V projection)
//      2 = bf16 out, sigmoid(v*scale)                               (scores -> P)
//      3 = fp32 out                                                 (PV -> out)
template <int EPI>
__global__ __launch_bounds__(256) void gemm_bt(
    const bf16_t* __restrict__ A, const bf16_t* __restrict__ Bt, void* __restrict__ Cout,
    const float* __restrict__ bias, int K, int lda, int ldb, int ldc, float scale,
    size_t sA, size_t sB, size_t sC) {
  __shared__ bf16_t As[BM * BK];
  __shared__ bf16_t Bs[BN * BK];
  const int tid = threadIdx.x;
  const int lane = tid & 63;
  const int w = tid >> 6;
  const int wr = (w >> 1) * 64;
  const int wc = (w & 1) * 64;
  const int fm = lane & 15;
  const int fko = (lane >> 4) * 8;

  const bf16_t* Ag = A + (size_t)blockIdx.z * sA + (size_t)blockIdx.y * BM * lda;
  const bf16_t* Bg = Bt + (size_t)blockIdx.z * sB + (size_t)blockIdx.x * BN * ldb;

  f32x4 acc[4][4] = {};

  for (int k0 = 0; k0 < K; k0 += BK) {
    stage128x32(Ag + k0, lda, As, tid);
    stage128x32(Bg + k0, ldb, Bs, tid);
    __syncthreads();  // drains vmcnt (global_load_lds) before barrier
    bf16x8 af[4], bfr[4];
#pragma unroll
    for (int i = 0; i < 4; ++i)
      af[i] = *(const bf16x8*)&As[(wr + i * 16 + fm) * BK + fko];
#pragma unroll
    for (int j = 0; j < 4; ++j)
      bfr[j] = *(const bf16x8*)&Bs[(wc + j * 16 + fm) * BK + fko];
#pragma unroll
    for (int i = 0; i < 4; ++i)
#pragma unroll
      for (int j = 0; j < 4; ++j)
        acc[i][j] = __builtin_amdgcn_mfma_f32_16x16x32_bf16(af[i], bfr[j], acc[i][j], 0, 0, 0);
    __syncthreads();
  }

  // epilogue: C/D layout col=lane&15, row=(lane>>4)*4+reg
  const int row0 = blockIdx.y * BM + wr + (lane >> 4) * 4;
  const int col0 = blockIdx.x * BN + wc + fm;
#pragma unroll
  for (int i = 0; i < 4; ++i) {
#pragma unroll
    for (int j = 0; j < 4; ++j) {
      const int n = col0 + j * 16;
#pragma unroll
      for (int r = 0; r < 4; ++r) {
        const int m = row0 + i * 16 + r;
        float v = acc[i][j][r];
        if constexpr (EPI == 0) {
          bf16_t* C = (bf16_t*)Cout + (size_t)blockIdx.z * sC;
          C[(size_t)m * ldc + n] = (bf16_t)(v + bias[n]);
        } else if constexpr (EPI == 1) {
          // m spans B*S; batch = m>>12 (S=4096), s = m & 4095; Vt[b][n][s]
          bf16_t* C = (bf16_t*)Cout;
          C[((size_t)(m >> 12) << 22) + (size_t)n * S_DIM + (m & (S_DIM - 1))] =
              (bf16_t)(v + bias[n]);
        } else if constexpr (EPI == 2) {
          bf16_t* C = (bf16_t*)Cout + (size_t)blockIdx.z * sC;
          float s = 1.0f / (1.0f + __expf(-v * scale));
          C[(size_t)m * ldc + n] = (bf16_t)s;
        } else {
          float* C = (float*)Cout + (size_t)blockIdx.z * sC;
          C[(size_t)m * ldc + n] = v;
        }
      }
    }
  }
}

extern "C" void kernel_launch(void* const* d_in, const int* in_sizes, int n_in,
                              void* d_out, int out_size, void* d_ws, size_t ws_size,
                              hipStream_t stream) {
  const float* X  = (const float*)d_in[0];
  const float* Wq = (const float*)d_in[1];
  const float* bq = (const float*)d_in[2];
  const float* Wk = (const float*)d_in[3];
  const float* bk = (const float*)d_in[4];
  const float* Wv = (const float*)d_in[5];
  const float* bv = (const float*)d_in[6];
  float* out = (float*)d_out;

  const int M = B_DIM * S_DIM;                 // 16384
  const size_t SD = (size_t)S_DIM * D_DIM;     // 4M  (per-batch Q/K/V elements)
  const size_t E  = (size_t)M * D_DIM;         // 16M
  const size_t PE1 = (size_t)S_DIM * S_DIM;    // 16M (one batch of P)
  const size_t WE = (size_t)D_DIM * D_DIM;

  // choose P capacity from ws_size: all-4-batch P if it fits, else per-batch
  size_t need4 = (4 * PE1 + 3 * E + 3 * WE) * sizeof(bf16_t);
  const int PB = (ws_size >= need4) ? 4 : 1;
  const size_t psz = (size_t)PB * PE1;

  bf16_t* ws = (bf16_t*)d_ws;
  bf16_t* P   = ws;      // P region
  bf16_t* Xb  = ws;      // aliases P: Xb dead before first P write (same-stream ordering)
  bf16_t* Qb  = ws + psz;
  bf16_t* Kb  = Qb + E;
  bf16_t* Vt  = Kb + E;  // [B][D][S]
  bf16_t* Wqt = Vt + E;
  bf16_t* Wkt = Wqt + WE;
  bf16_t* Wvt = Wkt + WE;

  // 1. cast X to bf16
  cast_f32_bf16<<<dim3((unsigned)(E / 8 / 256)), dim3(256), 0, stream>>>(X, Xb);

  // 2. transpose+cast weights
  dim3 tg(D_DIM / 32, D_DIM / 32), tb(32, 8);
  transpose_cast_1024<<<tg, tb, 0, stream>>>(Wq, Wqt);
  transpose_cast_1024<<<tg, tb, 0, stream>>>(Wk, Wkt);
  transpose_cast_1024<<<tg, tb, 0, stream>>>(Wv, Wvt);

  // 3. projections: [16384,1024] x [1024,1024]^T
  dim3 pg(D_DIM / BN, M / BM, 1);  // (8, 128)
  gemm_bt<0><<<pg, 256, 0, stream>>>(Xb, Wqt, Qb, bq, D_DIM, D_DIM, D_DIM, D_DIM, 1.0f, 0, 0, 0);
  gemm_bt<0><<<pg, 256, 0, stream>>>(Xb, Wkt, Kb, bk, D_DIM, D_DIM, D_DIM, D_DIM, 1.0f, 0, 0, 0);
  gemm_bt<1><<<pg, 256, 0, stream>>>(Xb, Wvt, Vt, bv, D_DIM, D_DIM, D_DIM, D_DIM, 1.0f, 0, 0, 0);

  // 4/5. scores (sigmoid fused) then PV, PB batches at a time
  const float scale = 0.03125f;  // 1/sqrt(1024)
  for (int b0 = 0; b0 < B_DIM; b0 += PB) {
    dim3 sg(S_DIM / BN, S_DIM / BM, PB);  // (32, 32, PB)
    gemm_bt<2><<<sg, 256, 0, stream>>>(Qb + (size_t)b0 * SD, Kb + (size_t)b0 * SD, P,
                                       nullptr, D_DIM, D_DIM, D_DIM, S_DIM, scale,
                                       SD, SD, PE1);
    dim3 vg(D_DIM / BN, S_DIM / BM, PB);  // (8, 32, PB)
    gemm_bt<3><<<vg, 256, 0, stream>>>(P, Vt + (size_t)b0 * SD, out + (size_t)b0 * SD,
                                       nullptr, S_DIM, S_DIM, S_DIM, D_DIM, 1.0f,
                                       PE1, SD, SD);
  }
}

// Round 2
// 633.177 us; speedup vs baseline: 1.2124x; 1.2124x over previous
//
#include <hip/hip_runtime.h>
#include <hip/hip_bf16.h>

typedef __bf16 bf16_t;
typedef bf16_t bf16x8 __attribute__((ext_vector_type(8)));
typedef float f32x4 __attribute__((ext_vector_type(4)));

constexpr int BM = 128, BN = 128, BK = 32;  // BK is the sub-tile K; we stage 2 per barrier
constexpr int D_DIM = 1024;
constexpr int S_DIM = 4096;
constexpr int B_DIM = 4;

// ---------------- elementwise cast X: fp32 -> bf16 ----------------
__global__ void cast_f32_bf16(const float* __restrict__ in, bf16_t* __restrict__ out) {
  size_t i = ((size_t)blockIdx.x * blockDim.x + threadIdx.x) * 8;
  float4 a = *(const float4*)(in + i);
  float4 b = *(const float4*)(in + i + 4);
  bf16x8 o;
  o[0] = (bf16_t)a.x; o[1] = (bf16_t)a.y; o[2] = (bf16_t)a.z; o[3] = (bf16_t)a.w;
  o[4] = (bf16_t)b.x; o[5] = (bf16_t)b.y; o[6] = (bf16_t)b.z; o[7] = (bf16_t)b.w;
  *(bf16x8*)(out + i) = o;
}

// ---------------- transpose + cast weight: [1024][1024] f32 -> bf16 transposed ----
__global__ void transpose_cast_1024(const float* __restrict__ in, bf16_t* __restrict__ out) {
  __shared__ float t[32][33];
  int x0 = blockIdx.x * 32, y0 = blockIdx.y * 32;
#pragma unroll
  for (int i = 0; i < 32; i += 8)
    t[threadIdx.y + i][threadIdx.x] =
        in[(size_t)(y0 + threadIdx.y + i) * D_DIM + (x0 + threadIdx.x)];
  __syncthreads();
#pragma unroll
  for (int i = 0; i < 32; i += 8)
    out[(size_t)(x0 + threadIdx.y + i) * D_DIM + (y0 + threadIdx.x)] =
        (bf16_t)t[threadIdx.x][threadIdx.y + i];
}

// ---------------- staging: 128x32 bf16 tile -> LDS via global_load_lds (16B/lane) ---------
__device__ __forceinline__ void stage128x32(const bf16_t* __restrict__ g, int ld,
                                            bf16_t* lds, int tid) {
  int w = tid >> 6;
  int r = tid >> 2;
  int c = (tid & 3) * 8;
  const bf16_t* g0 = g + (size_t)r * ld + c;
  const bf16_t* g1 = g0 + (size_t)64 * ld;
  bf16_t* l0 = lds + w * 512;  // wave-uniform base; HW adds lane*16B
  __builtin_amdgcn_global_load_lds((const __attribute__((address_space(1))) void*)g0,
                                   (__attribute__((address_space(3))) void*)l0, 16, 0, 0);
  __builtin_amdgcn_global_load_lds((const __attribute__((address_space(1))) void*)g1,
                                   (__attribute__((address_space(3))) void*)(l0 + 2048), 16, 0, 0);
}

// ---------------- gemm_bt: C[M,N] = A[M,K] * Bt[N,K]^T, bf16 in, fp32 acc ---------
// K-loop stages TWO 128x32 sub-tiles per operand per barrier pair (effective BK=64):
// halves the __syncthreads count vs round-1 while keeping the proven conflict-free
// BK=32 LDS layout (padding would break global_load_lds's lane-contiguous dest).
// EPI: 0 = fused QKV projection epilogue (Q,K row-major + bias; V transposed + bias)
//      2 = bf16 out, sigmoid(v*scale)      (scores -> P)
//      3 = fp32 out                         (PV -> out)
// SWAP: interpret grid as (x=row-blocks, y=col-blocks) for B-panel L2 locality.
template <int EPI, bool SWAP>
__global__ __launch_bounds__(256) void gemm_bt(
    const bf16_t* __restrict__ A, const bf16_t* __restrict__ Bt,
    void* __restrict__ C0, void* __restrict__ C1, void* __restrict__ C2,
    const float* __restrict__ b0, const float* __restrict__ b1, const float* __restrict__ b2,
    int K, int lda, int ldb, int ldc, float scale,
    size_t sA, size_t sB, size_t sC) {
  __shared__ bf16_t As[2 * BM * BK];  // two 128x32 halves, 16 KB
  __shared__ bf16_t Bs[2 * BN * BK];
  const int tid = threadIdx.x;
  const int lane = tid & 63;
  const int w = tid >> 6;
  const int wr = (w >> 1) * 64;
  const int wc = (w & 1) * 64;
  const int fm = lane & 15;
  const int fko = (lane >> 4) * 8;

  const int bx = SWAP ? blockIdx.y : blockIdx.x;
  const int by = SWAP ? blockIdx.x : blockIdx.y;

  const bf16_t* Ag = A + (size_t)blockIdx.z * sA + (size_t)by * BM * lda;
  const bf16_t* Bg = Bt + (size_t)blockIdx.z * sB + (size_t)bx * BN * ldb;

  f32x4 acc[4][4] = {};

  for (int k0 = 0; k0 < K; k0 += 2 * BK) {
    stage128x32(Ag + k0, lda, As, tid);
    stage128x32(Ag + k0 + BK, lda, As + BM * BK, tid);
    stage128x32(Bg + k0, ldb, Bs, tid);
    stage128x32(Bg + k0 + BK, ldb, Bs + BN * BK, tid);
    __syncthreads();
#pragma unroll
    for (int h = 0; h < 2; ++h) {
      const bf16_t* as = As + h * BM * BK;
      const bf16_t* bs = Bs + h * BN * BK;
      bf16x8 af[4], bfr[4];
#pragma unroll
      for (int i = 0; i < 4; ++i)
        af[i] = *(const bf16x8*)&as[(wr + i * 16 + fm) * BK + fko];
#pragma unroll
      for (int j = 0; j < 4; ++j)
        bfr[j] = *(const bf16x8*)&bs[(wc + j * 16 + fm) * BK + fko];
#pragma unroll
      for (int i = 0; i < 4; ++i)
#pragma unroll
        for (int j = 0; j < 4; ++j)
          acc[i][j] = __builtin_amdgcn_mfma_f32_16x16x32_bf16(af[i], bfr[j], acc[i][j], 0, 0, 0);
    }
    __syncthreads();
  }

  // epilogue: C/D layout col=lane&15, row=(lane>>4)*4+reg
  const int row0 = by * BM + wr + (lane >> 4) * 4;
  const int col0 = bx * BN + wc + fm;

  if constexpr (EPI == 0) {
    // fused QKV: N=3072; segment uniform per block (block cols are 128-aligned)
    const int seg = (bx * BN) >> 10;  // 0=Q, 1=K, 2=V
    const float* bias = (seg == 0) ? b0 : (seg == 1) ? b1 : b2;
#pragma unroll
    for (int i = 0; i < 4; ++i) {
#pragma unroll
      for (int j = 0; j < 4; ++j) {
        const int n = col0 + j * 16;
        const int nl = n & 1023;
        const float bv = bias[nl];
#pragma unroll
        for (int r = 0; r < 4; ++r) {
          const int m = row0 + i * 16 + r;
          float v = acc[i][j][r] + bv;
          if (seg < 2) {
            bf16_t* C = (bf16_t*)(seg == 0 ? C0 : C1);
            C[(size_t)m * D_DIM + nl] = (bf16_t)v;
          } else {
            // Vt[b][n][s]: b = m>>12, s = m&4095
            bf16_t* C = (bf16_t*)C2;
            C[((size_t)(m >> 12) << 22) + (size_t)nl * S_DIM + (m & (S_DIM - 1))] = (bf16_t)v;
          }
        }
      }
    }
  } else {
#pragma unroll
    for (int i = 0; i < 4; ++i) {
#pragma unroll
      for (int j = 0; j < 4; ++j) {
        const int n = col0 + j * 16;
#pragma unroll
        for (int r = 0; r < 4; ++r) {
          const int m = row0 + i * 16 + r;
          float v = acc[i][j][r];
          if constexpr (EPI == 2) {
            bf16_t* C = (bf16_t*)C0 + (size_t)blockIdx.z * sC;
            float s = 1.0f / (1.0f + __expf(-v * scale));
            C[(size_t)m * ldc + n] = (bf16_t)s;
          } else {
            float* C = (float*)C0 + (size_t)blockIdx.z * sC;
            C[(size_t)m * ldc + n] = v;
          }
        }
      }
    }
  }
}

extern "C" void kernel_launch(void* const* d_in, const int* in_sizes, int n_in,
                              void* d_out, int out_size, void* d_ws, size_t ws_size,
                              hipStream_t stream) {
  const float* X  = (const float*)d_in[0];
  const float* Wq = (const float*)d_in[1];
  const float* bq = (const float*)d_in[2];
  const float* Wk = (const float*)d_in[3];
  const float* bk = (const float*)d_in[4];
  const float* Wv = (const float*)d_in[5];
  const float* bv = (const float*)d_in[6];
  float* out = (float*)d_out;

  const int M = B_DIM * S_DIM;                 // 16384
  const size_t SD = (size_t)S_DIM * D_DIM;     // 4M per-batch Q/K/V elements
  const size_t E  = (size_t)M * D_DIM;         // 16M
  const size_t PE1 = (size_t)S_DIM * S_DIM;    // 16M (one batch of P)
  const size_t WE = (size_t)D_DIM * D_DIM;

  size_t need4 = (4 * PE1 + 3 * E + 3 * WE) * sizeof(bf16_t);
  const int PB = (ws_size >= need4) ? 4 : 1;
  const size_t psz = (size_t)PB * PE1;

  bf16_t* ws = (bf16_t*)d_ws;
  bf16_t* P   = ws;      // P region
  bf16_t* Xb  = ws;      // aliases P: Xb dead before first P write (same-stream ordering)
  bf16_t* Qb  = ws + psz;
  bf16_t* Kb  = Qb + E;
  bf16_t* Vt  = Kb + E;  // [B][D][S]
  bf16_t* Wt  = Vt + E;  // [3072][1024] concat of Wq^T, Wk^T, Wv^T

  // 1. cast X to bf16
  cast_f32_bf16<<<dim3((unsigned)(E / 8 / 256)), dim3(256), 0, stream>>>(X, Xb);

  // 2. transpose+cast weights into concatenated Wt
  dim3 tg(D_DIM / 32, D_DIM / 32), tb(32, 8);
  transpose_cast_1024<<<tg, tb, 0, stream>>>(Wq, Wt);
  transpose_cast_1024<<<tg, tb, 0, stream>>>(Wk, Wt + WE);
  transpose_cast_1024<<<tg, tb, 0, stream>>>(Wv, Wt + 2 * WE);

  // 3. fused QKV projection: [16384,1024] x [3072,1024]^T
  dim3 pg(3 * D_DIM / BN, M / BM, 1);  // (24, 128)
  gemm_bt<0, false><<<pg, 256, 0, stream>>>(Xb, Wt, Qb, Kb, Vt, bq, bk, bv,
                                            D_DIM, D_DIM, D_DIM, D_DIM, 1.0f, 0, 0, 0);

  // 4/5. scores (sigmoid fused) then PV, PB batches at a time
  const float scale = 0.03125f;  // 1/sqrt(1024)
  for (int b0 = 0; b0 < B_DIM; b0 += PB) {
    dim3 sg(S_DIM / BN, S_DIM / BM, PB);  // (32, 32, PB)
    gemm_bt<2, false><<<sg, 256, 0, stream>>>(Qb + (size_t)b0 * SD, Kb + (size_t)b0 * SD, P,
                                              nullptr, nullptr, nullptr, nullptr, nullptr,
                                              D_DIM, D_DIM, D_DIM, S_DIM, scale,
                                              SD, SD, PE1);
    // PV with swapped grid: x = row-blocks (32) so consecutive blocks share a Vt panel
    dim3 vg(S_DIM / BM, D_DIM / BN, PB);  // (32, 8, PB)
    gemm_bt<3, true><<<vg, 256, 0, stream>>>(P, Vt + (size_t)b0 * SD, out + (size_t)b0 * SD,
                                             nullptr, nullptr, nullptr, nullptr, nullptr,
                                             S_DIM, S_DIM, S_DIM, D_DIM, 1.0f,
                                             PE1, SD, SD);
  }
}